// Round 2
// baseline (3961.517 us; speedup 1.0000x reference)
//
#include <hip/hip_runtime.h>
#include <hip/hip_bf16.h>

// Transformer encoder-decoder forward, MI355X.
// S=696, T-1=511, B=64, D=128, H=4 (hd=32), L=3+3.
// Dtype-agnostic: detects bf16 vs f32 input buffers at runtime (enc_ln_w is all
// ones -> first u32 word 0x3F803F80 if bf16, 0x3F800000 if f32), normalizes all
// inputs to an f32 pool in workspace, computes in f32, writes output in the
// detected dtype.

typedef unsigned short u16;
typedef unsigned int u32;
typedef float f32x4 __attribute__((ext_vector_type(4)));
typedef float f32x2 __attribute__((ext_vector_type(2)));

static __device__ __forceinline__ float bf2f(u16 u) {
  u32 x = ((u32)u) << 16;
  return __builtin_bit_cast(float, x);
}
static __device__ __forceinline__ u16 f2bf(float f) {
  u32 x = __builtin_bit_cast(u32, f);
  u32 r = (x + 0x7fffu + ((x >> 16) & 1u)) >> 16;
  return (u16)r;
}

// ---------------- dtype detect + input normalize ----------------
__global__ void detect_k(const u32* __restrict__ ones, int* __restrict__ flag) {
  *flag = (ones[0] == 0x3F803F80u) ? 1 : 0;   // 1 = bf16 buffers, 0 = f32
}

struct CvtArgs {
  const void* p[32];
  int n[32];
  int off[32];
};

__global__ __launch_bounds__(256) void cvt_all(CvtArgs A, const int* __restrict__ flag,
                                               float* __restrict__ pool) {
  int ti = blockIdx.y;
  int i = blockIdx.x * 256 + threadIdx.x;
  int n = A.n[ti];
  if (i >= n) return;
  float v;
  if (*flag) v = bf2f(((const u16*)A.p[ti])[i]);
  else       v = ((const float*)A.p[ti])[i];
  pool[A.off[ti] + i] = v;
}

// ---------------- embed ----------------
__global__ void embed_enc(const float* __restrict__ src, const float* __restrict__ w,
                          const float* __restrict__ b, float* __restrict__ X) {
  int n = blockIdx.x;          // n = s*64 + bb
  int d = threadIdx.x;         // 0..127
  int s = n >> 6, bb = n & 63;
  float freq = __expf(-(float)(d & 126) * 0.07195578415606394f); // ln(10000)/128
  float arg = (float)s * freq;
  float pe = (d & 1) ? cosf(arg) : sinf(arg);
  float v = src[bb * 696 + s] * w[d] + b[d] + pe;
  X[(size_t)n * 128 + d] = v;
}

__global__ void embed_dec(const float* __restrict__ tgt, const float* __restrict__ w,
                          const float* __restrict__ b, float* __restrict__ Y) {
  int n = blockIdx.x;          // n = t*64 + bb
  int d = threadIdx.x;
  int tt = n >> 6, bb = n & 63;
  float v = tgt[bb * 512 + tt] * w[d] + b[d];
  if (tt == 0 && (d & 1)) v += 1.0f;   // pe[0]: sin(0)=0 even, cos(0)=1 odd
  Y[(size_t)n * 128 + d] = v;
}

// ---------------- GEMM: Y[N,M] = X[N,128] @ W[M,128]^T + bias, opt relu ------
__global__ __launch_bounds__(256) void gemm128(
    const float* __restrict__ X, const float* __restrict__ W,
    const float* __restrict__ bias, float* __restrict__ Y, int M, int relu) {
  __shared__ float Xs[64][65];
  __shared__ float Ws[64][65];
  const int t = threadIdx.x;
  const int n0 = blockIdx.x << 6, m0 = blockIdx.y << 6;
  const int ty = t >> 4, tx = t & 15;
  const int r0 = ty << 2, c0 = tx << 2;
  float acc[4][4] = {};

  for (int kk = 0; kk < 128; kk += 64) {
    __syncthreads();
#pragma unroll
    for (int i = 0; i < 4; ++i) {           // stage 64x64 of X and W
      int idx = t + (i << 8);               // 0..1023
      int r = idx >> 4, c = (idx & 15) << 2;
      *(f32x4*)&Xs[r][c] = *(const f32x4*)(X + (size_t)(n0 + r) * 128 + kk + c);
      *(f32x4*)&Ws[r][c] = *(const f32x4*)(W + (size_t)(m0 + r) * 128 + kk + c);
    }
    __syncthreads();
#pragma unroll 8
    for (int k = 0; k < 64; ++k) {
      float a0 = Xs[r0 + 0][k], a1 = Xs[r0 + 1][k], a2 = Xs[r0 + 2][k], a3 = Xs[r0 + 3][k];
      float b0 = Ws[c0 + 0][k], b1 = Ws[c0 + 1][k], b2 = Ws[c0 + 2][k], b3 = Ws[c0 + 3][k];
      acc[0][0] += a0 * b0; acc[0][1] += a0 * b1; acc[0][2] += a0 * b2; acc[0][3] += a0 * b3;
      acc[1][0] += a1 * b0; acc[1][1] += a1 * b1; acc[1][2] += a1 * b2; acc[1][3] += a1 * b3;
      acc[2][0] += a2 * b0; acc[2][1] += a2 * b1; acc[2][2] += a2 * b2; acc[2][3] += a2 * b3;
      acc[3][0] += a3 * b0; acc[3][1] += a3 * b1; acc[3][2] += a3 * b2; acc[3][3] += a3 * b3;
    }
  }
  float bv[4];
#pragma unroll
  for (int j = 0; j < 4; ++j) bv[j] = bias[m0 + c0 + j];
#pragma unroll
  for (int i = 0; i < 4; ++i) {
#pragma unroll
    for (int j = 0; j < 4; ++j) {
      float v = acc[i][j] + bv[j];
      if (relu) v = fmaxf(v, 0.0f);
      Y[(size_t)(n0 + r0 + i) * M + m0 + c0 + j] = v;
    }
  }
}

// ---------------- attention (flash-style, 64 q-rows per block) ----------------
__global__ __launch_bounds__(256) void attn_k(
    const float* __restrict__ Qb, int ldq,
    const float* __restrict__ Kb, int ldk,
    const float* __restrict__ Vb, int ldv,
    float* __restrict__ Ob, int Tq, int Tk, int causal) {
  __shared__ float Ks[64][36];
  __shared__ float Vs[64][36];
  __shared__ float Ps[64][66];
  const int t = threadIdx.x;
  const int b = blockIdx.y >> 2;
  const int h = blockIdx.y & 3;
  const int q0 = blockIdx.x << 6;
  const int qr = t >> 2;        // q-row within tile, 4 lanes per row
  const int dq = t & 3;
  const int d0 = dq << 3;       // this lane's 8 output dims
  const int tq = q0 + qr;
  const int tqc = tq < Tq ? tq : (Tq - 1);

  const float* qp = Qb + ((size_t)tqc * 64 + b) * ldq + h * 32;
  f32x4 qv[8];
#pragma unroll
  for (int i = 0; i < 8; ++i) qv[i] = *(const f32x4*)(qp + i * 4);

  float m = -1e30f, l = 0.0f;
  f32x4 o0 = 0.0f, o1 = 0.0f;
  const float scale = 0.17677669529663687f;  // 1/sqrt(32)

  const int kmax = causal ? (q0 + 64 < Tk ? q0 + 64 : Tk) : Tk;
  const int nkt = (kmax + 63) >> 6;

  for (int kt = 0; kt < nkt; ++kt) {
    const int k0 = kt << 6;
    __syncthreads();
#pragma unroll
    for (int i = 0; i < 2; ++i) {            // stage K,V tiles: 64x32 each
      int idx = t + (i << 8);
      int r = idx >> 3, c = (idx & 7) << 2;
      int j = k0 + r; if (j >= Tk) j = Tk - 1;
      size_t roff = (size_t)j * 64 + b;
      *(f32x4*)&Ks[r][c] = *(const f32x4*)(Kb + roff * ldk + h * 32 + c);
      *(f32x4*)&Vs[r][c] = *(const f32x4*)(Vb + roff * ldv + h * 32 + c);
    }
    __syncthreads();

    float sv[16];
    float smax = -1e30f;
#pragma unroll
    for (int i = 0; i < 16; ++i) {           // 16 scores per lane
      int kr = dq + (i << 2);
      f32x4 a4 = 0.0f;
#pragma unroll
      for (int c = 0; c < 8; ++c) a4 += qv[c] * (*(const f32x4*)&Ks[kr][c << 2]);
      float s = ((a4.x + a4.y) + (a4.z + a4.w)) * scale;
      int j = k0 + kr;
      bool ok = (j < Tk) && (!causal || j <= tq);
      s = ok ? s : -1e30f;
      sv[i] = s;
      smax = fmaxf(smax, s);
    }
    smax = fmaxf(smax, __shfl_xor(smax, 1));
    smax = fmaxf(smax, __shfl_xor(smax, 2));
    float mnew = fmaxf(m, smax);
    float corr = __expf(m - mnew);
    float lsum = 0.0f;
#pragma unroll
    for (int i = 0; i < 16; ++i) {
      int kr = dq + (i << 2);
      float p = __expf(sv[i] - mnew);
      Ps[qr][kr] = p;
      lsum += p;
    }
    lsum += __shfl_xor(lsum, 1);
    lsum += __shfl_xor(lsum, 2);
    l = l * corr + lsum;
    m = mnew;
    o0 *= corr; o1 *= corr;
#pragma unroll
    for (int kr = 0; kr < 64; ++kr) {        // PV accumulate (same-wave LDS)
      float p = Ps[qr][kr];
      o0 += p * (*(const f32x4*)&Vs[kr][d0]);
      o1 += p * (*(const f32x4*)&Vs[kr][d0 + 4]);
    }
  }

  if (tq < Tq) {
    float inv = 1.0f / l;
    float* op = Ob + ((size_t)tq * 64 + b) * 128 + h * 32 + d0;
    *(f32x4*)op = o0 * inv;
    *(f32x4*)(op + 4) = o1 * inv;
  }
}

// ---------------- residual + layernorm (in place on X) ----------------
__global__ __launch_bounds__(256) void ln_res(
    float* __restrict__ X, const float* __restrict__ A,
    const float* __restrict__ w, const float* __restrict__ bias) {
  int n = (blockIdx.x << 2) + (threadIdx.x >> 6);
  int lane = threadIdx.x & 63;
  float* xp = X + (size_t)n * 128 + (lane << 1);
  const float* ap = A + (size_t)n * 128 + (lane << 1);
  f32x2 x = *(f32x2*)xp;
  f32x2 a = *(const f32x2*)ap;
  f32x2 v = x + a;
  float s = v.x + v.y;
#pragma unroll
  for (int off = 1; off < 64; off <<= 1) s += __shfl_xor(s, off);
  float mean = s * 0.0078125f;
  f32x2 d = v - mean;
  float ss = d.x * d.x + d.y * d.y;
#pragma unroll
  for (int off = 1; off < 64; off <<= 1) ss += __shfl_xor(ss, off);
  float rstd = rsqrtf(ss * 0.0078125f + 1e-5f);
  f32x2 r;
  r.x = d.x * rstd * w[lane << 1] + bias[lane << 1];
  r.y = d.y * rstd * w[(lane << 1) + 1] + bias[(lane << 1) + 1];
  *(f32x2*)xp = r;
}

// ---------------- head: out[b*511+t] = Y[t*64+b,:] . w + bh ----------------
__global__ __launch_bounds__(256) void head_k(
    const float* __restrict__ Y, const float* __restrict__ w,
    const float* __restrict__ bh, void* __restrict__ out, const int* __restrict__ flag) {
  int n = (blockIdx.x << 2) + (threadIdx.x >> 6);
  int lane = threadIdx.x & 63;
  const float* yp = Y + (size_t)n * 128 + (lane << 1);
  float s = yp[0] * w[lane << 1] + yp[1] * w[(lane << 1) + 1];
#pragma unroll
  for (int off = 1; off < 64; off <<= 1) s += __shfl_xor(s, off);
  if (lane == 0) {
    int tt = n >> 6, bb = n & 63;
    float r = s + bh[0];
    int idx = bb * 511 + tt;
    if (*flag) ((u16*)out)[idx] = f2bf(r);
    else       ((float*)out)[idx] = r;
  }
}

// ---------------- host ----------------
extern "C" void kernel_launch(void* const* d_in, const int* in_sizes, int n_in,
                              void* d_out, int out_size, void* d_ws, size_t ws_size,
                              hipStream_t stream) {
  (void)out_size; (void)ws_size;
  // input offsets (prefix sum) for the f32 pool
  CvtArgs A;
  long off[33]; off[0] = 0;
  int maxn = 0;
  for (int i = 0; i < 32; ++i) {
    int n = (i < n_in) ? in_sizes[i] : 0;
    A.p[i] = (i < n_in) ? d_in[i] : d_in[0];
    A.n[i] = n;
    A.off[i] = (int)off[i];
    off[i + 1] = off[i] + n;
    if (n > maxn) maxn = n;
  }

  const size_t NE = 44544;  // 696*64
  const size_t ND = 32704;  // 511*64
  float* ws   = (float*)d_ws;
  int*   flag = (int*)d_ws;                       // 16 floats reserved
  float* Wp   = ws + 16;                          // f32 input pool
  float* Xe   = Wp + ((off[32] + 15) & ~15l);     // NE*128
  float* QKV  = Xe + NE * 128;                    // NE*384
  float* TMP  = QKV + NE * 384;                   // NE*128
  float* Yd   = TMP + NE * 128;                   // ND*128
  float* KVm  = QKV + ND * 128;                   // cross-attn KV inside QKV

  const float* src       = Wp + A.off[0];
  const float* tgt       = Wp + A.off[1];
  const float* emb_in_w  = Wp + A.off[2];
  const float* emb_in_b  = Wp + A.off[3];
  const float* emb_out_w = Wp + A.off[4];
  const float* emb_out_b = Wp + A.off[5];
  const float* enc_qkv_w = Wp + A.off[6];
  const float* enc_qkv_b = Wp + A.off[7];
  const float* enc_proj_w= Wp + A.off[8];
  const float* enc_proj_b= Wp + A.off[9];
  const float* enc_ff1_w = Wp + A.off[10];
  const float* enc_ff1_b = Wp + A.off[11];
  const float* enc_ff2_w = Wp + A.off[12];
  const float* enc_ff2_b = Wp + A.off[13];
  const float* enc_ln_w  = Wp + A.off[14];
  const float* enc_ln_b  = Wp + A.off[15];
  const float* dsa_qkv_w = Wp + A.off[16];
  const float* dsa_qkv_b = Wp + A.off[17];
  const float* dsa_proj_w= Wp + A.off[18];
  const float* dsa_proj_b= Wp + A.off[19];
  const float* dca_qkv_w = Wp + A.off[20];
  const float* dca_qkv_b = Wp + A.off[21];
  const float* dca_proj_w= Wp + A.off[22];
  const float* dca_proj_b= Wp + A.off[23];
  const float* dff1_w    = Wp + A.off[24];
  const float* dff1_b    = Wp + A.off[25];
  const float* dff2_w    = Wp + A.off[26];
  const float* dff2_b    = Wp + A.off[27];
  const float* dec_ln_w  = Wp + A.off[28];
  const float* dec_ln_b  = Wp + A.off[29];
  const float* head_w    = Wp + A.off[30];
  const float* head_b    = Wp + A.off[31];

  detect_k<<<1, 1, 0, stream>>>((const u32*)d_in[14], flag);
  cvt_all<<<dim3((maxn + 255) / 256, 32), 256, 0, stream>>>(A, flag, Wp);

  // ---------------- encoder ----------------
  embed_enc<<<dim3(44544), dim3(128), 0, stream>>>(src, emb_in_w, emb_in_b, Xe);
  for (int i = 0; i < 3; ++i) {
    gemm128<<<dim3(696, 6), 256, 0, stream>>>(Xe, enc_qkv_w + i * 49152, enc_qkv_b + i * 384, QKV, 384, 0);
    attn_k<<<dim3(11, 256), 256, 0, stream>>>(QKV, 384, QKV + 128, 384, QKV + 256, 384, TMP, 696, 696, 0);
    gemm128<<<dim3(696, 2), 256, 0, stream>>>(TMP, enc_proj_w + i * 16384, enc_proj_b + i * 128, QKV, 128, 0);
    ln_res<<<dim3(11136), 256, 0, stream>>>(Xe, QKV, enc_ln_w + (i * 2 + 0) * 128, enc_ln_b + (i * 2 + 0) * 128);
    gemm128<<<dim3(696, 2), 256, 0, stream>>>(Xe, enc_ff1_w + i * 16384, enc_ff1_b + i * 128, TMP, 128, 1);
    gemm128<<<dim3(696, 2), 256, 0, stream>>>(TMP, enc_ff2_w + i * 16384, enc_ff2_b + i * 128, QKV, 128, 0);
    ln_res<<<dim3(11136), 256, 0, stream>>>(Xe, QKV, enc_ln_w + (i * 2 + 1) * 128, enc_ln_b + (i * 2 + 1) * 128);
  }

  // ---------------- decoder ----------------
  embed_dec<<<dim3(32704), dim3(128), 0, stream>>>(tgt, emb_out_w, emb_out_b, Yd);
  for (int i = 0; i < 3; ++i) {
    gemm128<<<dim3(511, 6), 256, 0, stream>>>(Yd, dsa_qkv_w + i * 49152, dsa_qkv_b + i * 384, QKV, 384, 0);
    attn_k<<<dim3(8, 256), 256, 0, stream>>>(QKV, 384, QKV + 128, 384, QKV + 256, 384, TMP, 511, 511, 1);
    gemm128<<<dim3(511, 2), 256, 0, stream>>>(TMP, dsa_proj_w + i * 16384, dsa_proj_b + i * 128, QKV, 128, 0);
    ln_res<<<dim3(8176), 256, 0, stream>>>(Yd, QKV, dec_ln_w + (i * 3 + 0) * 128, dec_ln_b + (i * 3 + 0) * 128);
    // cross-attn: Q from Yd, K/V from encoder memory Xe
    gemm128<<<dim3(511, 2), 256, 0, stream>>>(Yd, dca_qkv_w + i * 49152, dca_qkv_b + i * 384, QKV, 128, 0);
    gemm128<<<dim3(696, 4), 256, 0, stream>>>(Xe, dca_qkv_w + i * 49152 + 16384, dca_qkv_b + i * 384 + 128, KVm, 256, 0);
    attn_k<<<dim3(8, 256), 256, 0, stream>>>(QKV, 128, KVm, 256, KVm + 128, 256, TMP, 511, 696, 0);
    gemm128<<<dim3(511, 2), 256, 0, stream>>>(TMP, dca_proj_w + i * 16384, dca_proj_b + i * 128, QKV, 128, 0);
    ln_res<<<dim3(8176), 256, 0, stream>>>(Yd, QKV, dec_ln_w + (i * 3 + 1) * 128, dec_ln_b + (i * 3 + 1) * 128);
    gemm128<<<dim3(511, 2), 256, 0, stream>>>(Yd, dff1_w + i * 16384, dff1_b + i * 128, TMP, 128, 1);
    gemm128<<<dim3(511, 2), 256, 0, stream>>>(TMP, dff2_w + i * 16384, dff2_b + i * 128, QKV, 128, 0);
    ln_res<<<dim3(8176), 256, 0, stream>>>(Yd, QKV, dec_ln_w + (i * 3 + 2) * 128, dec_ln_b + (i * 3 + 2) * 128);
  }

  head_k<<<dim3(8176), 256, 0, stream>>>(Yd, head_w, head_b, d_out, flag);
}

// Round 3
// 1243.397 us; speedup vs baseline: 3.1860x; 3.1860x over previous
//
#include <hip/hip_runtime.h>
#include <hip/hip_bf16.h>

// Transformer encoder-decoder forward, MI355X (gfx950), MFMA bf16 version.
// S=696, T-1=511, B=64, D=128, H=4 (hd=32), L=3+3.
// Residual stream f32; all matmuls via v_mfma_f32_16x16x32_bf16 with bf16
// operand copies written by producers. Dtype-agnostic input handling
// (detects bf16 vs f32 via enc_ln_w ones pattern).

typedef unsigned short u16;
typedef unsigned int u32;
typedef float f32x4 __attribute__((ext_vector_type(4)));
typedef float f32x2 __attribute__((ext_vector_type(2)));
typedef unsigned short u16x8 __attribute__((ext_vector_type(8)));
typedef __bf16 bf16x8 __attribute__((ext_vector_type(8)));

static __device__ __forceinline__ float bf2f(u16 u) {
  u32 x = ((u32)u) << 16;
  return __builtin_bit_cast(float, x);
}
static __device__ __forceinline__ u16 f2bf(float f) {
  u32 x = __builtin_bit_cast(u32, f);
  u32 r = (x + 0x7fffu + ((x >> 16) & 1u)) >> 16;
  return (u16)r;
}
static __device__ __forceinline__ f32x4 mfma16(bf16x8 a, bf16x8 b, f32x4 c) {
  return __builtin_amdgcn_mfma_f32_16x16x32_bf16(a, b, c, 0, 0, 0);
}

// ---------------- dtype detect + input normalize ----------------
__global__ void detect_k(const u32* __restrict__ ones, int* __restrict__ flag) {
  *flag = (ones[0] == 0x3F803F80u) ? 1 : 0;   // 1 = bf16 buffers, 0 = f32
}

struct CvtArgs {
  const void* p[32];
  int n[32];
  int off[32];
};

__global__ __launch_bounds__(256) void cvt_all(CvtArgs A, const int* __restrict__ flag,
                                               float* __restrict__ poolf,
                                               u16* __restrict__ poolb) {
  int ti = blockIdx.y;
  int i = blockIdx.x * 256 + threadIdx.x;
  int n = A.n[ti];
  if (i >= n) return;
  int o = A.off[ti] + i;
  if (*flag) {
    u16 raw = ((const u16*)A.p[ti])[i];
    poolb[o] = raw;
    poolf[o] = bf2f(raw);
  } else {
    float v = ((const float*)A.p[ti])[i];
    poolf[o] = v;
    poolb[o] = f2bf(v);
  }
}

// ---------------- embed ----------------
__global__ void embed_enc(const float* __restrict__ src, const float* __restrict__ w,
                          const float* __restrict__ b, float* __restrict__ X,
                          u16* __restrict__ Xb) {
  int n = blockIdx.x;          // n = s*64 + bb
  int d = threadIdx.x;         // 0..127
  int s = n >> 6, bb = n & 63;
  float freq = __expf(-(float)(d & 126) * 0.07195578415606394f); // ln(10000)/128
  float arg = (float)s * freq;
  float pe = (d & 1) ? cosf(arg) : sinf(arg);
  float v = src[bb * 696 + s] * w[d] + b[d] + pe;
  X[(size_t)n * 128 + d] = v;
  Xb[(size_t)n * 128 + d] = f2bf(v);
}

__global__ void embed_dec(const float* __restrict__ tgt, const float* __restrict__ w,
                          const float* __restrict__ b, float* __restrict__ Y,
                          u16* __restrict__ Yb) {
  int n = blockIdx.x;          // n = t*64 + bb
  int d = threadIdx.x;
  int tt = n >> 6, bb = n & 63;
  float v = tgt[bb * 512 + tt] * w[d] + b[d];
  if (tt == 0 && (d & 1)) v += 1.0f;   // pe[0]: sin(0)=0 even, cos(0)=1 odd
  Y[(size_t)n * 128 + d] = v;
  Yb[(size_t)n * 128 + d] = f2bf(v);
}

// ------------- MFMA GEMM: Y[N,M] = Xb[N,128] @ Wb[M,128]^T + bias -------------
// 64x64 tile, 4 waves in 2x2, K=128 staged in LDS once.
__global__ __launch_bounds__(256) void gemm_mf(
    const u16* __restrict__ Xb, const u16* __restrict__ Wb,
    const float* __restrict__ bias, float* __restrict__ Yf,
    u16* __restrict__ Yb, int M, int relu) {
  __shared__ u16 Xs[64][136];
  __shared__ u16 Ws[64][136];
  const int t = threadIdx.x;
  const int n0 = blockIdx.x << 6, m0 = blockIdx.y << 6;
  const int wq = t >> 6, lane = t & 63, lg = lane >> 4, lr = lane & 15;
  const int wr = (wq >> 1) << 5, wc = (wq & 1) << 5;

#pragma unroll
  for (int i = 0; i < 4; ++i) {
    int idx = t + (i << 8);                 // 0..1023
    int r = idx >> 4, c = (idx & 15) << 3;  // 16B chunks
    *(u16x8*)&Xs[r][c] = *(const u16x8*)(Xb + (size_t)(n0 + r) * 128 + c);
    *(u16x8*)&Ws[r][c] = *(const u16x8*)(Wb + (size_t)(m0 + r) * 128 + c);
  }
  __syncthreads();

  f32x4 acc00 = {0,0,0,0}, acc01 = {0,0,0,0}, acc10 = {0,0,0,0}, acc11 = {0,0,0,0};
#pragma unroll
  for (int ks = 0; ks < 4; ++ks) {
    bf16x8 a0 = *(const bf16x8*)&Xs[wr + lr][(ks << 5) + (lg << 3)];
    bf16x8 a1 = *(const bf16x8*)&Xs[wr + 16 + lr][(ks << 5) + (lg << 3)];
    bf16x8 b0 = *(const bf16x8*)&Ws[wc + lr][(ks << 5) + (lg << 3)];
    bf16x8 b1 = *(const bf16x8*)&Ws[wc + 16 + lr][(ks << 5) + (lg << 3)];
    acc00 = mfma16(a0, b0, acc00);
    acc01 = mfma16(a0, b1, acc01);
    acc10 = mfma16(a1, b0, acc10);
    acc11 = mfma16(a1, b1, acc11);
  }

  f32x4 accs[2][2] = {{acc00, acc01}, {acc10, acc11}};
#pragma unroll
  for (int mi = 0; mi < 2; ++mi) {
#pragma unroll
    for (int ni = 0; ni < 2; ++ni) {
      int col = m0 + wc + (ni << 4) + lr;
      float bv = bias[col];
#pragma unroll
      for (int r = 0; r < 4; ++r) {
        int row = n0 + wr + (mi << 4) + (lg << 2) + r;
        float v = accs[mi][ni][r] + bv;
        if (relu) v = fmaxf(v, 0.0f);
        size_t o = (size_t)row * M + col;
        if (Yf) Yf[o] = v;
        if (Yb) Yb[o] = f2bf(v);
      }
    }
  }
}

// ------------- MFMA flash attention: 64 q-rows per block, hd=32 -------------
__global__ __launch_bounds__(256) void attn_mf(
    const u16* __restrict__ Qb, int ldq,
    const u16* __restrict__ Kb, int ldk,
    const u16* __restrict__ Vb, int ldv,
    u16* __restrict__ Ob, int Tq, int Tk, int causal) {
  __shared__ u16 Ks[64][40];
  __shared__ u16 Vt[32][72];
  __shared__ u16 Ps[4][16][72];
  const int t = threadIdx.x;
  const int wq = t >> 6, lane = t & 63, lg = lane >> 4, lr = lane & 15;
  const int b = blockIdx.y >> 2, h = blockIdx.y & 3;
  const int q0 = blockIdx.x << 6;
  const int qw = q0 + (wq << 4);

  int qload = qw + lr; if (qload > Tq - 1) qload = Tq - 1;
  bf16x8 qfrag = *(const bf16x8*)(Qb + ((size_t)qload * 64 + b) * ldq + h * 32 + (lg << 3));

  f32x4 o0 = {0,0,0,0}, o1 = {0,0,0,0};
  float m[4] = {-1e30f, -1e30f, -1e30f, -1e30f};
  float l[4] = {0.0f, 0.0f, 0.0f, 0.0f};
  const float scale = 0.17677669529663687f;  // 1/sqrt(32)

  const int kmaxv = causal ? ((q0 + 64 < Tk) ? q0 + 64 : Tk) : Tk;
  const int nkt = (kmaxv + 63) >> 6;
  const int srow = t >> 2, scoff = (t & 3) << 3;

  for (int kt = 0; kt < nkt; ++kt) {
    const int k0 = kt << 6;
    __syncthreads();
    {
      int j = k0 + srow; if (j > Tk - 1) j = Tk - 1;
      *(u16x8*)&Ks[srow][scoff] = *(const u16x8*)(Kb + ((size_t)j * 64 + b) * ldk + h * 32 + scoff);
      u16x8 vv = *(const u16x8*)(Vb + ((size_t)j * 64 + b) * ldv + h * 32 + scoff);
#pragma unroll
      for (int e = 0; e < 8; ++e) Vt[scoff + e][srow] = vv[e];
    }
    __syncthreads();

    float sf[4][4];
#pragma unroll
    for (int kc = 0; kc < 4; ++kc) {
      bf16x8 kb = *(const bf16x8*)&Ks[(kc << 4) + lr][lg << 3];
      f32x4 z = {0,0,0,0};
      f32x4 s = mfma16(qfrag, kb, z);
      int j = k0 + (kc << 4) + lr;
#pragma unroll
      for (int r = 0; r < 4; ++r) {
        int qr = qw + (lg << 2) + r;
        bool ok = (j < Tk) && (!causal || j <= qr);
        sf[kc][r] = ok ? s[r] * scale : -1e30f;
      }
    }

    float corr[4], lsum[4];
#pragma unroll
    for (int r = 0; r < 4; ++r) {
      float mx = fmaxf(fmaxf(sf[0][r], sf[1][r]), fmaxf(sf[2][r], sf[3][r]));
      mx = fmaxf(mx, __shfl_xor(mx, 1));
      mx = fmaxf(mx, __shfl_xor(mx, 2));
      mx = fmaxf(mx, __shfl_xor(mx, 4));
      mx = fmaxf(mx, __shfl_xor(mx, 8));
      float mn = fmaxf(m[r], mx);
      corr[r] = __expf(m[r] - mn);
      m[r] = mn;
      lsum[r] = 0.0f;
    }
#pragma unroll
    for (int kc = 0; kc < 4; ++kc) {
#pragma unroll
      for (int r = 0; r < 4; ++r) {
        float p = __expf(sf[kc][r] - m[r]);
        lsum[r] += p;
        Ps[wq][(lg << 2) + r][(kc << 4) + lr] = f2bf(p);
      }
    }
#pragma unroll
    for (int r = 0; r < 4; ++r) {
      float ls = lsum[r];
      ls += __shfl_xor(ls, 1);
      ls += __shfl_xor(ls, 2);
      ls += __shfl_xor(ls, 4);
      ls += __shfl_xor(ls, 8);
      l[r] = l[r] * corr[r] + ls;
      o0[r] *= corr[r];
      o1[r] *= corr[r];
    }
#pragma unroll
    for (int kc2 = 0; kc2 < 2; ++kc2) {
      bf16x8 pa = *(const bf16x8*)&Ps[wq][lr][(kc2 << 5) + (lg << 3)];
      bf16x8 v0 = *(const bf16x8*)&Vt[lr][(kc2 << 5) + (lg << 3)];
      bf16x8 v1 = *(const bf16x8*)&Vt[16 + lr][(kc2 << 5) + (lg << 3)];
      o0 = mfma16(pa, v0, o0);
      o1 = mfma16(pa, v1, o1);
    }
  }

#pragma unroll
  for (int r = 0; r < 4; ++r) {
    int row = qw + (lg << 2) + r;
    if (row < Tq) {
      float inv = 1.0f / l[r];
      size_t base = ((size_t)row * 64 + b) * 128 + h * 32;
      Ob[base + lr] = f2bf(o0[r] * inv);
      Ob[base + 16 + lr] = f2bf(o1[r] * inv);
    }
  }
}

// ---------------- residual + layernorm (in place on X, + bf16 copy) ----------
__global__ __launch_bounds__(256) void ln_res(
    float* __restrict__ X, u16* __restrict__ Xb, const float* __restrict__ A,
    const float* __restrict__ w, const float* __restrict__ bias) {
  int n = (blockIdx.x << 2) + (threadIdx.x >> 6);
  int lane = threadIdx.x & 63;
  float* xp = X + (size_t)n * 128 + (lane << 1);
  const float* ap = A + (size_t)n * 128 + (lane << 1);
  f32x2 x = *(f32x2*)xp;
  f32x2 a = *(const f32x2*)ap;
  f32x2 v = x + a;
  float s = v.x + v.y;
#pragma unroll
  for (int off = 1; off < 64; off <<= 1) s += __shfl_xor(s, off);
  float mean = s * 0.0078125f;
  f32x2 d = v - mean;
  float ss = d.x * d.x + d.y * d.y;
#pragma unroll
  for (int off = 1; off < 64; off <<= 1) ss += __shfl_xor(ss, off);
  float rstd = rsqrtf(ss * 0.0078125f + 1e-5f);
  f32x2 r;
  r.x = d.x * rstd * w[lane << 1] + bias[lane << 1];
  r.y = d.y * rstd * w[(lane << 1) + 1] + bias[(lane << 1) + 1];
  *(f32x2*)xp = r;
  u32 pk = (u32)f2bf(r.x) | ((u32)f2bf(r.y) << 16);
  *(u32*)(Xb + (size_t)n * 128 + (lane << 1)) = pk;
}

// ---------------- head: out[b*511+t] = Y[t*64+b,:] . w + bh ----------------
__global__ __launch_bounds__(256) void head_k(
    const float* __restrict__ Y, const float* __restrict__ w,
    const float* __restrict__ bh, void* __restrict__ out, const int* __restrict__ flag) {
  int n = (blockIdx.x << 2) + (threadIdx.x >> 6);
  int lane = threadIdx.x & 63;
  const float* yp = Y + (size_t)n * 128 + (lane << 1);
  float s = yp[0] * w[lane << 1] + yp[1] * w[(lane << 1) + 1];
#pragma unroll
  for (int off = 1; off < 64; off <<= 1) s += __shfl_xor(s, off);
  if (lane == 0) {
    int tt = n >> 6, bb = n & 63;
    float r = s + bh[0];
    int idx = bb * 511 + tt;
    if (*flag) ((u16*)out)[idx] = f2bf(r);
    else       ((float*)out)[idx] = r;
  }
}

// ---------------- host ----------------
extern "C" void kernel_launch(void* const* d_in, const int* in_sizes, int n_in,
                              void* d_out, int out_size, void* d_ws, size_t ws_size,
                              hipStream_t stream) {
  (void)out_size; (void)ws_size;
  CvtArgs A;
  long off[33]; off[0] = 0;
  int maxn = 0;
  for (int i = 0; i < 32; ++i) {
    int n = (i < n_in) ? in_sizes[i] : 0;
    A.p[i] = (i < n_in) ? d_in[i] : d_in[0];
    A.n[i] = n;
    A.off[i] = (int)off[i];
    off[i + 1] = off[i] + n;
    if (n > maxn) maxn = n;
  }
  const size_t offA = (size_t)((off[32] + 15) & ~15l);

  const size_t NE = 44544;  // 696*64
  const size_t ND = 32704;  // 511*64
  float* ws   = (float*)d_ws;
  int*   flag = (int*)d_ws;                 // 16 floats reserved
  float* Wp   = ws + 16;                    // f32 input pool
  float* Xe   = Wp + offA;                  // NE*128 f32 residual (encoder)
  float* Af   = Xe + NE * 128;              // NE*128 f32 gemm-out for ln
  float* Yd   = Af + NE * 128;              // ND*128 f32 residual (decoder)
  u16*   U    = (u16*)(Yd + ND * 128);
  u16*   Wb   = U;                          // bf16 input pool
  u16*   Xebf = Wb + offA;                  // NE*128
  u16*   QKVbf= Xebf + NE * 128;            // NE*384
  u16*   TMPbf= QKVbf + NE * 384;           // NE*128
  u16*   Ydbf = TMPbf + NE * 128;           // ND*128
  u16*   KVbf = QKVbf + ND * 128;           // cross KV (NE*256) inside QKVbf

  const float* F = Wp;
  detect_k<<<1, 1, 0, stream>>>((const u32*)d_in[14], flag);
  cvt_all<<<dim3((maxn + 255) / 256, 32), 256, 0, stream>>>(A, flag, Wp, Wb);

  // ---------------- encoder ----------------
  embed_enc<<<dim3(44544), dim3(128), 0, stream>>>(F + A.off[0], F + A.off[2], F + A.off[3], Xe, Xebf);
  for (int i = 0; i < 3; ++i) {
    gemm_mf<<<dim3(696, 6), 256, 0, stream>>>(Xebf, Wb + A.off[6] + i * 49152, F + A.off[7] + i * 384, nullptr, QKVbf, 384, 0);
    attn_mf<<<dim3(11, 256), 256, 0, stream>>>(QKVbf, 384, QKVbf + 128, 384, QKVbf + 256, 384, TMPbf, 696, 696, 0);
    gemm_mf<<<dim3(696, 2), 256, 0, stream>>>(TMPbf, Wb + A.off[8] + i * 16384, F + A.off[9] + i * 128, Af, nullptr, 128, 0);
    ln_res<<<dim3(11136), 256, 0, stream>>>(Xe, Xebf, Af, F + A.off[14] + (i * 2 + 0) * 128, F + A.off[15] + (i * 2 + 0) * 128);
    gemm_mf<<<dim3(696, 2), 256, 0, stream>>>(Xebf, Wb + A.off[10] + i * 16384, F + A.off[11] + i * 128, nullptr, TMPbf, 128, 1);
    gemm_mf<<<dim3(696, 2), 256, 0, stream>>>(TMPbf, Wb + A.off[12] + i * 16384, F + A.off[13] + i * 128, Af, nullptr, 128, 0);
    ln_res<<<dim3(11136), 256, 0, stream>>>(Xe, Xebf, Af, F + A.off[14] + (i * 2 + 1) * 128, F + A.off[15] + (i * 2 + 1) * 128);
  }

  // ---------------- decoder ----------------
  embed_dec<<<dim3(32704), dim3(128), 0, stream>>>(F + A.off[1], F + A.off[4], F + A.off[5], Yd, Ydbf);
  for (int i = 0; i < 3; ++i) {
    gemm_mf<<<dim3(511, 6), 256, 0, stream>>>(Ydbf, Wb + A.off[16] + i * 49152, F + A.off[17] + i * 384, nullptr, QKVbf, 384, 0);
    attn_mf<<<dim3(8, 256), 256, 0, stream>>>(QKVbf, 384, QKVbf + 128, 384, QKVbf + 256, 384, TMPbf, 511, 511, 1);
    gemm_mf<<<dim3(511, 2), 256, 0, stream>>>(TMPbf, Wb + A.off[18] + i * 16384, F + A.off[19] + i * 128, Af, nullptr, 128, 0);
    ln_res<<<dim3(8176), 256, 0, stream>>>(Yd, Ydbf, Af, F + A.off[28] + (i * 3 + 0) * 128, F + A.off[29] + (i * 3 + 0) * 128);
    // cross-attn: Q from Yd, K/V from encoder memory
    gemm_mf<<<dim3(511, 2), 256, 0, stream>>>(Ydbf, Wb + A.off[20] + i * 49152, F + A.off[21] + i * 384, nullptr, QKVbf, 128, 0);
    gemm_mf<<<dim3(696, 4), 256, 0, stream>>>(Xebf, Wb + A.off[20] + i * 49152 + 16384, F + A.off[21] + i * 384 + 128, nullptr, KVbf, 256, 0);
    attn_mf<<<dim3(8, 256), 256, 0, stream>>>(QKVbf, 128, KVbf, 256, KVbf + 128, 256, TMPbf, 511, 696, 0);
    gemm_mf<<<dim3(511, 2), 256, 0, stream>>>(TMPbf, Wb + A.off[22] + i * 16384, F + A.off[23] + i * 128, Af, nullptr, 128, 0);
    ln_res<<<dim3(8176), 256, 0, stream>>>(Yd, Ydbf, Af, F + A.off[28] + (i * 3 + 1) * 128, F + A.off[29] + (i * 3 + 1) * 128);
    gemm_mf<<<dim3(511, 2), 256, 0, stream>>>(Ydbf, Wb + A.off[24] + i * 16384, F + A.off[25] + i * 128, nullptr, TMPbf, 128, 1);
    gemm_mf<<<dim3(511, 2), 256, 0, stream>>>(TMPbf, Wb + A.off[26] + i * 16384, F + A.off[27] + i * 128, Af, nullptr, 128, 0);
    ln_res<<<dim3(8176), 256, 0, stream>>>(Yd, Ydbf, Af, F + A.off[28] + (i * 3 + 2) * 128, F + A.off[29] + (i * 3 + 2) * 128);
  }

  head_k<<<dim3(8176), 256, 0, stream>>>(Yd, F + A.off[30], F + A.off[31], d_out, flag);
}